// Round 1
// baseline (115.748 us; speedup 1.0000x reference)
//
#include <hip/hip_runtime.h>
#include <math.h>

#define BATCH 4096
#define SEQ   180
#define EMBED 256
#define EPSN  1e-12f

// One 64-lane wave per batch row. Lane l owns floats [4l, 4l+3] of the
// 256-dim accumulator, so each token's embedding row is gathered with a
// single coalesced 1KB wave transaction (float4 per lane).
__global__ __launch_bounds__(256) void linreg_embedbag_kernel(
    const int*   __restrict__ samples,  // [BATCH, SEQ] int32, -1 = pad
    const float* __restrict__ emb,      // [VOCAB, EMBED]
    const float* __restrict__ W,        // [1, EMBED]
    const float* __restrict__ b,        // [1]
    float*       __restrict__ out)      // [BATCH]
{
    const int wave = (int)((blockIdx.x * blockDim.x + threadIdx.x) >> 6);
    const int lane = (int)(threadIdx.x & 63);
    if (wave >= BATCH) return;

    const float4* __restrict__ embv = reinterpret_cast<const float4*>(emb);
    const int*    __restrict__ srow = samples + (size_t)wave * SEQ;

    float4 acc = make_float4(0.f, 0.f, 0.f, 0.f);

    #pragma unroll 4
    for (int t = 0; t < SEQ; ++t) {
        const int idx = srow[t];          // wave-uniform load (scalarized)
        if (idx >= 0) {                   // wave-uniform branch
            const float4 e = embv[(size_t)idx * 64 + lane];
            acc.x += e.x; acc.y += e.y; acc.z += e.z; acc.w += e.w;
        }
    }

    // per-lane partials for norm^2 and dot(summed, W)
    const float4 w4 = reinterpret_cast<const float4*>(W)[lane];
    float dot  = acc.x * w4.x + acc.y * w4.y + acc.z * w4.z + acc.w * w4.w;
    float nrm2 = acc.x * acc.x + acc.y * acc.y + acc.z * acc.z + acc.w * acc.w;

    // wave-64 butterfly reduction
    #pragma unroll
    for (int off = 32; off > 0; off >>= 1) {
        dot  += __shfl_down(dot,  off, 64);
        nrm2 += __shfl_down(nrm2, off, 64);
    }

    if (lane == 0) {
        const float norm  = fmaxf(sqrtf(nrm2), EPSN);
        const float logit = dot / norm + b[0];
        out[wave] = 1.0f / (1.0f + expf(-logit));
    }
}

extern "C" void kernel_launch(void* const* d_in, const int* in_sizes, int n_in,
                              void* d_out, int out_size, void* d_ws, size_t ws_size,
                              hipStream_t stream) {
    const int*   samples = (const int*)  d_in[0];
    const float* emb     = (const float*)d_in[1];
    const float* W       = (const float*)d_in[2];
    const float* b       = (const float*)d_in[3];
    float*       out     = (float*)d_out;

    // 1 wave per row, 4 waves (256 threads) per block
    const int blocks = (BATCH * 64) / 256;  // 1024
    linreg_embedbag_kernel<<<blocks, 256, 0, stream>>>(samples, emb, W, b, out);
}

// Round 2
// 110.724 us; speedup vs baseline: 1.0454x; 1.0454x over previous
//
#include <hip/hip_runtime.h>
#include <math.h>

#define BATCH 4096
#define SEQ   180
#define EMBED 256
#define EPSN  1e-12f

// Two 64-lane waves per batch row (each handles a contiguous half of SEQ);
// lane l owns floats [4l, 4l+3] of the 256-dim accumulator, so each token's
// embedding row is one coalesced 1KB wave transaction (float4/lane).
// Partial vectors are combined through LDS, then wave 0 does the epilogue.
// 4096 rows x 2 waves = 8192 waves = 32 waves/CU -> full occupancy.
__global__ __launch_bounds__(256) void linreg_embedbag_kernel(
    const int*   __restrict__ samples,  // [BATCH, SEQ] int32, -1 = pad
    const float* __restrict__ emb,      // [VOCAB, EMBED]
    const float* __restrict__ W,        // [1, EMBED]
    const float* __restrict__ b,        // [1]
    float*       __restrict__ out)      // [BATCH]
{
    const int wid  = (int)(threadIdx.x >> 6);   // 0..3
    const int lane = (int)(threadIdx.x & 63);
    const int rowInBlock = wid >> 1;            // 0..1
    const int sub        = wid & 1;             // 0 = first half, 1 = second half
    const int row  = blockIdx.x * 2 + rowInBlock;

    const float4* __restrict__ embv = reinterpret_cast<const float4*>(emb);
    const int*    __restrict__ srow = samples + (size_t)row * SEQ;

    const int t0 = sub * (SEQ / 2);             // 0 or 90
    const int t1 = t0 + (SEQ / 2);              // 90 or 180

    float4 acc = make_float4(0.f, 0.f, 0.f, 0.f);

    // Branch-free: padding (-1) is ~1/100001 of tokens; gather row 0 and
    // multiply by mask instead of branching, so gathers pipeline freely.
    #pragma unroll 6
    for (int t = t0; t < t1; ++t) {
        const int idx = srow[t];                     // wave-uniform
        const int j   = idx >= 0 ? idx : 0;
        const float m = idx >= 0 ? 1.0f : 0.0f;
        const float4 e = embv[(size_t)j * 64 + lane];
        acc.x = fmaf(m, e.x, acc.x);
        acc.y = fmaf(m, e.y, acc.y);
        acc.z = fmaf(m, e.z, acc.z);
        acc.w = fmaf(m, e.w, acc.w);
    }

    __shared__ float4 part[2][64];
    if (sub == 1) part[rowInBlock][lane] = acc;
    __syncthreads();

    if (sub == 0) {
        const float4 o = part[rowInBlock][lane];
        acc.x += o.x; acc.y += o.y; acc.z += o.z; acc.w += o.w;

        const float4 w4 = reinterpret_cast<const float4*>(W)[lane];
        float dot  = acc.x * w4.x + acc.y * w4.y + acc.z * w4.z + acc.w * w4.w;
        float nrm2 = acc.x * acc.x + acc.y * acc.y + acc.z * acc.z + acc.w * acc.w;

        #pragma unroll
        for (int off = 32; off > 0; off >>= 1) {
            dot  += __shfl_down(dot,  off, 64);
            nrm2 += __shfl_down(nrm2, off, 64);
        }

        if (lane == 0) {
            const float norm  = fmaxf(sqrtf(nrm2), EPSN);
            const float logit = dot / norm + b[0];
            out[row] = 1.0f / (1.0f + expf(-logit));
        }
    }
}

extern "C" void kernel_launch(void* const* d_in, const int* in_sizes, int n_in,
                              void* d_out, int out_size, void* d_ws, size_t ws_size,
                              hipStream_t stream) {
    const int*   samples = (const int*)  d_in[0];
    const float* emb     = (const float*)d_in[1];
    const float* W       = (const float*)d_in[2];
    const float* b       = (const float*)d_in[3];
    float*       out     = (float*)d_out;

    // 2 rows per 256-thread block (2 waves per row)
    const int blocks = BATCH / 2;  // 2048
    linreg_embedbag_kernel<<<blocks, 256, 0, stream>>>(samples, emb, W, b, out);
}